// Round 17
// baseline (620.815 us; speedup 1.0000x reference)
//
#include <hip/hip_runtime.h>

#define N_NODES 50000
#define N_EDGES 10000
#define N_INC   800000
// IN_F=64, HID=64, concat width 128.
// R20/R21: scattered partial-sector stores cost full 32B sectors (HW fact).
// R23-R28: owner-scan binning. R29: fused LN+activation preps -> 609us (best).
// R30/R33: coarse-bucket bin3 81.4us + half-bucket hist/unbin -> 611.8/614.7
// (trade band, ~noise). R32: dual-chain append regressed (lesson: append body
// is exec-mask-serialized, not cnt-chain-bound).
// R34: k_bin3 at 128 threads/block (both waves are owner waves after load;
// 256-thread version idled 2 of 4 waves) + stage caps 20/24 (3sigma, spill
// path covers tail) -> LDS 12.1KB -> ~26 owner-waves/CU vs 16. Same tiles,
// same semantics. Everything else = R33 (passed).

#define NBK4   49     // node buckets (1024 nodes each)
#define EBK4   40     // edge buckets (256 edges each)
#define NG4    17408  // global node bucket cap
#define EG4    21248  // global edge bucket cap
#define NC4    20     // per-owner stage cap (tile 512: mean 10.45, ~3sigma)
#define EC4    24     // per-owner stage cap (tile 512: mean 12.8, ~3.2sigma)
#define NST4   21     // node stage stride (coprime with 32 banks)
#define EST4   25     // edge stage stride (coprime with 32 banks)
#define BIN_T  128    // bin3 block size (2 waves, both owners)
#define NH2    (2*NBK4)   // 98 node half-buckets (512 nodes)
#define EH2    (2*EBK4)   // 80 edge half-buckets (128 edges; #79 empty, guarded)
#define SLCAP  12288  // unbin half-slice staging cap (u16)

__device__ float bf2f(unsigned short u){
    return __uint_as_float(((unsigned)u) << 16);
}
__device__ unsigned short f2bf(float f){
    unsigned u = __float_as_uint(f);
    unsigned r = u + 0x7FFFu + ((u >> 16) & 1u);
    return (unsigned short)(r >> 16);
}
__device__ float ldv(const void* p, int i, int bf){
    if (bf) return bf2f(((const unsigned short*)p)[i]);
    return ((const float*)p)[i];
}
__device__ int ldnt_i(const int* p){ return __builtin_nontemporal_load(p); }

#define ACC8(A) float A##0=0.f,A##1=0.f,A##2=0.f,A##3=0.f,A##4=0.f,A##5=0.f,A##6=0.f,A##7=0.f
#define FMA8(A,a,b) A##0+=(a)*u0+(b)*v0; A##1+=(a)*u1+(b)*v1; A##2+=(a)*u2+(b)*v2; \
                    A##3+=(a)*u3+(b)*v3; A##4+=(a)*u4+(b)*v4; A##5+=(a)*u5+(b)*v5; \
                    A##6+=(a)*u6+(b)*v6; A##7+=(a)*u7+(b)*v7
#define STORE8(A,o) (o)[0]=f2bf(A##0);(o)[1]=f2bf(A##1);(o)[2]=f2bf(A##2);(o)[3]=f2bf(A##3); \
                    (o)[4]=f2bf(A##4);(o)[5]=f2bf(A##5);(o)[6]=f2bf(A##6);(o)[7]=f2bf(A##7)

__global__ void k_detect(const unsigned short* hw, int* flag){
    if (blockIdx.x == 0 && threadIdx.x == 0){
        int ok = 1;
        for (int j = 0; j < 64; ++j){
            float v = bf2f(hw[j]);
            if (!(v > 0.05f && v < 1.2f)) ok = 0;
        }
        *flag = ok;
    }
}

__global__ void k_zero(float* p, int n){
    int i = blockIdx.x*256 + threadIdx.x;
    if (i < n) p[i] = 0.f;
}

// Pass 1: owner-scan binning, coarse buckets, dual pre-packed arrays,
// single append chain. 128 threads/block: wave0 lanes 0-48 = node owners,
// wave1 lanes 0-39 (tid 64-103) = edge owners — no idle waves after load.
__global__ void k_bin3(const int* nidx, const int* eidx,
                       int* gntail, unsigned* nbuf,
                       int* getail, unsigned* ebuf){
    __shared__ __align__(16) unsigned nv[512];
    __shared__ __align__(16) unsigned ev[512];
    __shared__ unsigned nstage[NBK4*NST4];
    __shared__ unsigned estage[EBK4*EST4];
    int tid = threadIdx.x;
    int base_i = blockIdx.x*512;
    for (int k = tid; k < 512; k += BIN_T){
        int i = base_i + k;
        unsigned a = 0xFFFFFFFFu, c = 0xFFFFFFFFu;
        if (i < N_INC){
            unsigned n = (unsigned)ldnt_i(nidx + i);
            unsigned e = (unsigned)ldnt_i(eidx + i);
            a = (n << 16) | e;             // node-order pack
            c = (e << 16) | n;             // edge-order pack
        }
        nv[k] = a; ev[k] = c;
    }
    __syncthreads();
    bool isn = (tid < NBK4);
    bool ise = (tid >= 64 && tid < 64 + EBK4);
    if (!isn && !ise) return;
    int b = isn ? tid : (tid - 64);
    int sh = isn ? 26 : 24;
    const unsigned* src = isn ? nv : ev;
    int cap = isn ? NC4 : EC4;
    unsigned* stage = isn ? (nstage + b*NST4) : (estage + b*EST4);
    int* gtail = isn ? gntail : getail;
    unsigned* gbuf = isn ? nbuf : ebuf;
    int gcap = isn ? NG4 : EG4;
    int cnt = 0;
    const uint4* s4 = (const uint4*)src;
    for (int k4 = 0; k4 < 128; k4 += 2){
        uint4 va = s4[k4], vb = s4[k4+1];
#define CHK(V) { if (((V) >> sh) == (unsigned)b){ \
            if (cnt < cap) stage[cnt] = (V); \
            else { int q = atomicAdd(&gtail[b], 1); \
                   if (q < gcap) gbuf[(size_t)b*gcap + q] = (V); } \
            ++cnt; } }
        CHK(va.x) CHK(va.y) CHK(va.z) CHK(va.w)
        CHK(vb.x) CHK(vb.y) CHK(vb.z) CHK(vb.w)
#undef CHK
    }
    if (cnt > cap) cnt = cap;
    if (cnt > 0){
        int rb = atomicAdd(&gtail[b], cnt);
        for (int k = 0; k < cnt; ++k){
            int q = rb + k;
            if (q < gcap) gbuf[(size_t)b*gcap + q] = stage[k];
        }
    }
}

// Pass 2a: half-bucket LDS histogram -> Dc / Bc. Grid NH2+EH2=178; each block
// scans its parent bucket and filters to its half-range. Empty halves guarded.
__global__ void k_hist2(const int* gntail, const unsigned* nbuf, int* Dc,
                        const int* getail, const unsigned* ebuf, int* Bc){
    __shared__ int cnt[512];
    int b = blockIdx.x, tid = threadIdx.x;
    if (b < NH2){
        int bucket = b >> 1;
        int n0h = bucket*1024 + (b & 1)*512;
        if (n0h >= N_NODES) return;          // empty half (safety)
        for (int k = tid; k < 512; k += 256) cnt[k] = 0;
        __syncthreads();
        int m = gntail[bucket]; if (m > NG4) m = NG4;
        for (int idx = tid; idx < m; idx += 256){
            unsigned v = nbuf[(size_t)bucket*NG4 + idx];
            unsigned d = (v >> 16) - (unsigned)n0h;
            if (d < 512u) atomicAdd(&cnt[d], 1);
        }
        __syncthreads();
        for (int k = tid; k < 512; k += 256){
            int n = n0h + k;
            if (n < N_NODES) Dc[n] = cnt[k];
        }
    } else {
        int eh = b - NH2;
        int bucket = eh >> 1;
        int e0h = bucket*256 + (eh & 1)*128;
        if (e0h >= N_EDGES) return;          // empty half (eh=79: e0h=10112)
        for (int k = tid; k < 128; k += 256) cnt[k] = 0;
        __syncthreads();
        int m = getail[bucket]; if (m > EG4) m = EG4;
        for (int idx = tid; idx < m; idx += 256){
            unsigned v = ebuf[(size_t)bucket*EG4 + idx];
            unsigned d = (v >> 16) - (unsigned)e0h;
            if (d < 128u) atomicAdd(&cnt[d], 1);
        }
        __syncthreads();
        for (int k = tid; k < 128; k += 256){
            int e = e0h + k;
            if (e < N_EDGES) Bc[e] = cnt[k];
        }
    }
}

// Pass 2b: half-bucket scatter in LDS staging, coalesced CSR-slice write.
// Empty halves guarded (R31 crash lesson).
__global__ void k_unbin2(const int* gntail, const unsigned* nbuf,
                         const int* indptr_n, unsigned short* nlist,
                         const int* getail, const unsigned* ebuf,
                         const int* indptr_e, unsigned short* elist){
    __shared__ int cur[512];
    __shared__ unsigned short sl[SLCAP];   // 24.6KB
    int b = blockIdx.x, tid = threadIdx.x;
    if (b < NH2){
        int bucket = b >> 1;
        int n0h = bucket*1024 + (b & 1)*512;
        if (n0h >= N_NODES) return;          // empty half (safety)
        int base = indptr_n[n0h];
        for (int k = tid; k < 512; k += 256){
            int n = n0h + k;
            cur[k] = (n < N_NODES ? indptr_n[n] : N_INC) - base;
        }
        __syncthreads();
        int m = gntail[bucket]; if (m > NG4) m = NG4;
        for (int idx = tid; idx < m; idx += 256){
            unsigned v = nbuf[(size_t)bucket*NG4 + idx];
            unsigned d = (v >> 16) - (unsigned)n0h;
            if (d < 512u){
                int p = atomicAdd(&cur[d], 1);
                if (p < SLCAP) sl[p] = (unsigned short)(v & 0xFFFFu);
            }
        }
        __syncthreads();
        int end = (n0h + 512 >= N_NODES) ? N_INC : indptr_n[n0h + 512];
        int len = end - base;
        if (len > SLCAP) len = SLCAP;
        for (int i2 = tid; i2 < len; i2 += 256) nlist[base + i2] = sl[i2];
    } else {
        int eh = b - NH2;
        int bucket = eh >> 1;
        int e0h = bucket*256 + (eh & 1)*128;
        if (e0h >= N_EDGES) return;          // empty half (eh=79: e0h=10112)
        int base = indptr_e[e0h];
        for (int k = tid; k < 128; k += 256){
            int e = e0h + k;
            cur[k] = (e < N_EDGES ? indptr_e[e] : N_INC) - base;
        }
        __syncthreads();
        int m = getail[bucket]; if (m > EG4) m = EG4;
        for (int idx = tid; idx < m; idx += 256){
            unsigned v = ebuf[(size_t)bucket*EG4 + idx];
            unsigned d = (v >> 16) - (unsigned)e0h;
            if (d < 128u){
                int p = atomicAdd(&cur[d], 1);
                if (p < SLCAP) sl[p] = (unsigned short)(v & 0xFFFFu);
            }
        }
        __syncthreads();
        int end = (e0h + 128 >= N_EDGES) ? N_INC : indptr_e[e0h + 128];
        int len = end - base;
        if (len > SLCAP) len = SLCAP;
        for (int i2 = tid; i2 < len; i2 += 256) elist[base + i2] = sl[i2];
    }
}

// Binv from Bc
__global__ void k_binv(const int* Bc, float* Binv){
    int i = blockIdx.x*256 + threadIdx.x;
    if (i < N_EDGES) Binv[i] = Bc[i] > 0 ? 1.f/(float)Bc[i] : 0.f;
}

// Dinv via CSR: D[n] = sum hw[e] over incident edges (nlist u16), then invert.
__global__ void k_dinv(const int* indptr_n, const int* Dc,
                       const unsigned short* nlist, const void* hw,
                       float* Dinv, const int* flag){
    int bf = *flag;
    int n = blockIdx.x*256 + threadIdx.x;
    if (n >= N_NODES) return;
    int beg = indptr_n[n], cnt = Dc[n];
    float s = 0.f;
    int j = 0;
    for (; j + 4 <= cnt; j += 4){
        int e0 = nlist[beg+j+0], e1 = nlist[beg+j+1],
            e2 = nlist[beg+j+2], e3 = nlist[beg+j+3];
        float h0 = ldv(hw, e0, bf), h1 = ldv(hw, e1, bf),
              h2 = ldv(hw, e2, bf), h3 = ldv(hw, e3, bf);
        s += h0; s += h1; s += h2; s += h3;
    }
    for (; j < cnt; ++j){
        int e = nlist[beg + j];
        s += ldv(hw, e, bf);
    }
    Dinv[n] = s > 0.f ? 1.f/s : 0.f;
}

// ---- chunked exclusive scan, no LDS ----
__global__ void k_chunksum(const int* cnt, int* csum, int n, int nchunks){
    int ch = blockIdx.x*256 + threadIdx.x;
    if (ch >= nchunks) return;
    int beg = ch*128, end = beg + 128;
    if (end > n) end = n;
    int s = 0;
    for (int i = beg; i < end; ++i) s += cnt[i];
    csum[ch] = s;
}
__global__ void k_chunkscan(const int* csum, int* cbase, int nchunks){
    if (blockIdx.x == 0 && threadIdx.x == 0){
        int run = 0;
        for (int ch = 0; ch < nchunks; ++ch){
            cbase[ch] = run;
            run += csum[ch];
        }
    }
}
__global__ void k_chunkfill(const int* cnt, const int* cbase, int* indptr,
                            int n, int nchunks){
    int ch = blockIdx.x*256 + threadIdx.x;
    if (ch >= nchunks) return;
    int beg = ch*128, end = beg + 128;
    if (end > n) end = n;
    int run = cbase[ch];
    for (int i = beg; i < end; ++i){
        indptr[i] = run;
        run += cnt[i];
    }
}

// gate GEMM v3: 4 nodes x 8 cols per thread (block = 64 nodes x 128 cols).
__global__ void k_gemm_gate(const void* x, const void* st, const void* W,
                            unsigned short* X1b, const int* flag){
    int bf = *flag;
    int tid = threadIdx.x;
    int c0 = (tid & 15) * 8;
    int n0 = blockIdx.x*64 + (tid >> 4)*4;
    int g0 = n0 < N_NODES, g1 = n0+1 < N_NODES, g2 = n0+2 < N_NODES, g3 = n0+3 < N_NODES;
    ACC8(A); ACC8(B); ACC8(C); ACC8(D);
    int i0 = n0*64;
    if (bf){
        const unsigned short* Wh = (const unsigned short*)W;
        const unsigned short* xh = (const unsigned short*)x;
        const unsigned short* sh = (const unsigned short*)st;
        for (int k = 0; k < 64; ++k){
            const unsigned short* w0 = Wh + k*128 + c0;
            const unsigned short* w1 = w0 + 64*128;
            float u0=bf2f(w0[0]),u1=bf2f(w0[1]),u2=bf2f(w0[2]),u3=bf2f(w0[3]),
                  u4=bf2f(w0[4]),u5=bf2f(w0[5]),u6=bf2f(w0[6]),u7=bf2f(w0[7]);
            float v0=bf2f(w1[0]),v1=bf2f(w1[1]),v2=bf2f(w1[2]),v3=bf2f(w1[3]),
                  v4=bf2f(w1[4]),v5=bf2f(w1[5]),v6=bf2f(w1[6]),v7=bf2f(w1[7]);
            float a, b;
            a = g0?bf2f(xh[i0+k]):0.f;     b = g0?bf2f(sh[i0+k]):0.f;     FMA8(A,a,b);
            a = g1?bf2f(xh[i0+64+k]):0.f;  b = g1?bf2f(sh[i0+64+k]):0.f;  FMA8(B,a,b);
            a = g2?bf2f(xh[i0+128+k]):0.f; b = g2?bf2f(sh[i0+128+k]):0.f; FMA8(C,a,b);
            a = g3?bf2f(xh[i0+192+k]):0.f; b = g3?bf2f(sh[i0+192+k]):0.f; FMA8(D,a,b);
        }
    } else {
        const float* Wf = (const float*)W;
        const float* xf = (const float*)x;
        const float* sf = (const float*)st;
        for (int k = 0; k < 64; ++k){
            const float* w0 = Wf + k*128 + c0;
            const float* w1 = w0 + 64*128;
            float u0=w0[0],u1=w0[1],u2=w0[2],u3=w0[3],u4=w0[4],u5=w0[5],u6=w0[6],u7=w0[7];
            float v0=w1[0],v1=w1[1],v2=w1[2],v3=w1[3],v4=w1[4],v5=w1[5],v6=w1[6],v7=w1[7];
            float a, b;
            a = g0?xf[i0+k]:0.f;     b = g0?sf[i0+k]:0.f;     FMA8(A,a,b);
            a = g1?xf[i0+64+k]:0.f;  b = g1?sf[i0+64+k]:0.f;  FMA8(B,a,b);
            a = g2?xf[i0+128+k]:0.f; b = g2?sf[i0+128+k]:0.f; FMA8(C,a,b);
            a = g3?xf[i0+192+k]:0.f; b = g3?sf[i0+192+k]:0.f; FMA8(D,a,b);
        }
    }
    if (g0){ unsigned short* o = X1b + n0*128 + c0;       STORE8(A,o); }
    if (g1){ unsigned short* o = X1b + (n0+1)*128 + c0;   STORE8(B,o); }
    if (g2){ unsigned short* o = X1b + (n0+2)*128 + c0;   STORE8(C,o); }
    if (g3){ unsigned short* o = X1b + (n0+3)*128 + c0;   STORE8(D,o); }
}

// cand GEMM v3: same tiling; cols 0-63 from Wc, 64-127 from Wr; second operand rs (f32).
__global__ void k_gemm_cand(const void* x, const float* rs, const void* Wc,
                            const void* Wr, unsigned short* X1b, const int* flag){
    int bf = *flag;
    int tid = threadIdx.x;
    int cq = tid & 15;
    int c0 = cq * 8;
    int cc = c0 & 63;
    int n0 = blockIdx.x*64 + (tid >> 4)*4;
    int g0 = n0 < N_NODES, g1 = n0+1 < N_NODES, g2 = n0+2 < N_NODES, g3 = n0+3 < N_NODES;
    const void* Wsel = (cq < 8) ? Wc : Wr;
    ACC8(A); ACC8(B); ACC8(C); ACC8(D);
    int i0 = n0*64;
    if (bf){
        const unsigned short* Wh = (const unsigned short*)Wsel;
        const unsigned short* xh = (const unsigned short*)x;
        for (int k = 0; k < 64; ++k){
            const unsigned short* w0 = Wh + k*64 + cc;
            const unsigned short* w1 = w0 + 64*64;
            float u0=bf2f(w0[0]),u1=bf2f(w0[1]),u2=bf2f(w0[2]),u3=bf2f(w0[3]),
                  u4=bf2f(w0[4]),u5=bf2f(w0[5]),u6=bf2f(w0[6]),u7=bf2f(w0[7]);
            float v0=bf2f(w1[0]),v1=bf2f(w1[1]),v2=bf2f(w1[2]),v3=bf2f(w1[3]),
                  v4=bf2f(w1[4]),v5=bf2f(w1[5]),v6=bf2f(w1[6]),v7=bf2f(w1[7]);
            float a, b;
            a = g0?bf2f(xh[i0+k]):0.f;     b = g0?rs[i0+k]:0.f;     FMA8(A,a,b);
            a = g1?bf2f(xh[i0+64+k]):0.f;  b = g1?rs[i0+64+k]:0.f;  FMA8(B,a,b);
            a = g2?bf2f(xh[i0+128+k]):0.f; b = g2?rs[i0+128+k]:0.f; FMA8(C,a,b);
            a = g3?bf2f(xh[i0+192+k]):0.f; b = g3?rs[i0+192+k]:0.f; FMA8(D,a,b);
        }
    } else {
        const float* Wf = (const float*)Wsel;
        const float* xf = (const float*)x;
        for (int k = 0; k < 64; ++k){
            const float* w0 = Wf + k*64 + cc;
            const float* w1 = w0 + 64*64;
            float u0=w0[0],u1=w0[1],u2=w0[2],u3=w0[3],u4=w0[4],u5=w0[5],u6=w0[6],u7=w0[7];
            float v0=w1[0],v1=w1[1],v2=w1[2],v3=w1[3],v4=w1[4],v5=w1[5],v6=w1[6],v7=w1[7];
            float a, b;
            a = g0?xf[i0+k]:0.f;     b = g0?rs[i0+k]:0.f;     FMA8(A,a,b);
            a = g1?xf[i0+64+k]:0.f;  b = g1?rs[i0+64+k]:0.f;  FMA8(B,a,b);
            a = g2?xf[i0+128+k]:0.f; b = g2?rs[i0+128+k]:0.f; FMA8(C,a,b);
            a = g3?xf[i0+192+k]:0.f; b = g3?rs[i0+192+k]:0.f; FMA8(D,a,b);
        }
    }
    if (g0){ unsigned short* o = X1b + n0*128 + c0;       STORE8(A,o); }
    if (g1){ unsigned short* o = X1b + (n0+1)*128 + c0;   STORE8(B,o); }
    if (g2){ unsigned short* o = X1b + (n0+2)*128 + c0;   STORE8(C,o); }
    if (g3){ unsigned short* o = X1b + (n0+3)*128 + c0;   STORE8(D,o); }
}

// gate edge gather (64 threads/edge, all 128 cols in one traversal). Unroll-by-8.
__global__ void k_gather_e_gate(const int* indptr_e, const int* Bc,
                                const unsigned short* elist,
                                const unsigned short* X1b, const void* hw,
                                const float* Binv, unsigned* mb, const int* flag){
    int bf = *flag;
    int t = blockIdx.x*256 + threadIdx.x;
    if (t >= N_EDGES*64) return;
    int e = t >> 6, p = t & 63;          // pair index 0..63 (128 bf16 cols)
    int beg = indptr_e[e], cnt = Bc[e];
    float acc0 = 0.f, acc1 = 0.f;
    int j = 0;
    for (; j + 8 <= cnt; j += 8){
        int n0 = elist[beg+j+0], n1 = elist[beg+j+1],
            n2 = elist[beg+j+2], n3 = elist[beg+j+3],
            n4 = elist[beg+j+4], n5 = elist[beg+j+5],
            n6 = elist[beg+j+6], n7 = elist[beg+j+7];
        unsigned w0 = *(const unsigned*)(X1b + n0*128 + p*2);
        unsigned w1 = *(const unsigned*)(X1b + n1*128 + p*2);
        unsigned w2 = *(const unsigned*)(X1b + n2*128 + p*2);
        unsigned w3 = *(const unsigned*)(X1b + n3*128 + p*2);
        unsigned w4 = *(const unsigned*)(X1b + n4*128 + p*2);
        unsigned w5 = *(const unsigned*)(X1b + n5*128 + p*2);
        unsigned w6 = *(const unsigned*)(X1b + n6*128 + p*2);
        unsigned w7 = *(const unsigned*)(X1b + n7*128 + p*2);
        acc0 += bf2f((unsigned short)(w0 & 0xFFFFu)); acc1 += bf2f((unsigned short)(w0 >> 16));
        acc0 += bf2f((unsigned short)(w1 & 0xFFFFu)); acc1 += bf2f((unsigned short)(w1 >> 16));
        acc0 += bf2f((unsigned short)(w2 & 0xFFFFu)); acc1 += bf2f((unsigned short)(w2 >> 16));
        acc0 += bf2f((unsigned short)(w3 & 0xFFFFu)); acc1 += bf2f((unsigned short)(w3 >> 16));
        acc0 += bf2f((unsigned short)(w4 & 0xFFFFu)); acc1 += bf2f((unsigned short)(w4 >> 16));
        acc0 += bf2f((unsigned short)(w5 & 0xFFFFu)); acc1 += bf2f((unsigned short)(w5 >> 16));
        acc0 += bf2f((unsigned short)(w6 & 0xFFFFu)); acc1 += bf2f((unsigned short)(w6 >> 16));
        acc0 += bf2f((unsigned short)(w7 & 0xFFFFu)); acc1 += bf2f((unsigned short)(w7 >> 16));
    }
    for (; j < cnt; ++j){
        int n = elist[beg + j];
        unsigned v = *(const unsigned*)(X1b + n*128 + p*2);
        acc0 += bf2f((unsigned short)(v & 0xFFFFu));
        acc1 += bf2f((unsigned short)(v >> 16));
    }
    float wsc = ldv(hw, e, bf) * Binv[e];
    unsigned lo = f2bf(acc0 * wsc);
    unsigned hi = f2bf(acc1 * wsc);
    mb[e*64 + p] = lo | (hi << 16);
}

// cand edge gather: 32 threads/edge, cols 0-63 of X1 (CP=32). Unroll-by-8.
__global__ void k_gather_e2(const int* indptr_e, const int* Bc,
                            const unsigned short* elist,
                            const unsigned short* X1b, const void* hw,
                            const float* Binv, unsigned* mb, int pairBase, int CP,
                            const int* flag){
    int bf = *flag;
    int t = blockIdx.x*256 + threadIdx.x;
    if (t >= N_EDGES*32) return;
    int e = t >> 5, p = t & 31;
    int cp = pairBase + p;
    int beg = indptr_e[e], cnt = Bc[e];
    float acc0 = 0.f, acc1 = 0.f;
    int j = 0;
    for (; j + 8 <= cnt; j += 8){
        int n0 = elist[beg+j+0], n1 = elist[beg+j+1],
            n2 = elist[beg+j+2], n3 = elist[beg+j+3],
            n4 = elist[beg+j+4], n5 = elist[beg+j+5],
            n6 = elist[beg+j+6], n7 = elist[beg+j+7];
        unsigned w0 = *(const unsigned*)(X1b + n0*128 + cp*2);
        unsigned w1 = *(const unsigned*)(X1b + n1*128 + cp*2);
        unsigned w2 = *(const unsigned*)(X1b + n2*128 + cp*2);
        unsigned w3 = *(const unsigned*)(X1b + n3*128 + cp*2);
        unsigned w4 = *(const unsigned*)(X1b + n4*128 + cp*2);
        unsigned w5 = *(const unsigned*)(X1b + n5*128 + cp*2);
        unsigned w6 = *(const unsigned*)(X1b + n6*128 + cp*2);
        unsigned w7 = *(const unsigned*)(X1b + n7*128 + cp*2);
        acc0 += bf2f((unsigned short)(w0 & 0xFFFFu)); acc1 += bf2f((unsigned short)(w0 >> 16));
        acc0 += bf2f((unsigned short)(w1 & 0xFFFFu)); acc1 += bf2f((unsigned short)(w1 >> 16));
        acc0 += bf2f((unsigned short)(w2 & 0xFFFFu)); acc1 += bf2f((unsigned short)(w2 >> 16));
        acc0 += bf2f((unsigned short)(w3 & 0xFFFFu)); acc1 += bf2f((unsigned short)(w3 >> 16));
        acc0 += bf2f((unsigned short)(w4 & 0xFFFFu)); acc1 += bf2f((unsigned short)(w4 >> 16));
        acc0 += bf2f((unsigned short)(w5 & 0xFFFFu)); acc1 += bf2f((unsigned short)(w5 >> 16));
        acc0 += bf2f((unsigned short)(w6 & 0xFFFFu)); acc1 += bf2f((unsigned short)(w6 >> 16));
        acc0 += bf2f((unsigned short)(w7 & 0xFFFFu)); acc1 += bf2f((unsigned short)(w7 >> 16));
    }
    for (; j < cnt; ++j){
        int n = elist[beg + j];
        unsigned v = *(const unsigned*)(X1b + n*128 + cp*2);
        acc0 += bf2f((unsigned short)(v & 0xFFFFu));
        acc1 += bf2f((unsigned short)(v >> 16));
    }
    float wsc = ldv(hw, e, bf) * Binv[e];
    unsigned lo = f2bf(acc0 * wsc);
    unsigned hi = f2bf(acc1 * wsc);
    mb[e*CP + cp] = lo | (hi << 16);     // CP = C/2 pairs per edge
}

// R29: fused node gather + gate prep + row-LN + sigmoid -> zbuf/rs.
__global__ void k_prep_fin_gate(const int* indptr_n, const int* Dc,
                                const unsigned short* nlist, const unsigned* mb,
                                const void* x, const void* st,
                                const float* Dinv, const void* gb,
                                const void* lng, const void* lnb,
                                float* zbuf, float* rs, const int* flag){
    int bf = *flag;
    int t = blockIdx.x*256 + threadIdx.x;
    if (t >= N_NODES*32) return;
    int n = t >> 5, g = t & 31;
    int c = g*4;
    int beg = indptr_n[n], cnt = Dc[n];
    float a0 = 0.f, a1 = 0.f, a2 = 0.f, a3 = 0.f;
    int j = 0;
    for (; j + 4 <= cnt; j += 4){
        int e0 = nlist[beg+j+0], e1 = nlist[beg+j+1],
            e2 = nlist[beg+j+2], e3 = nlist[beg+j+3];
        const unsigned* q0 = mb + e0*64 + g*2;
        const unsigned* q1 = mb + e1*64 + g*2;
        const unsigned* q2 = mb + e2*64 + g*2;
        const unsigned* q3 = mb + e3*64 + g*2;
        unsigned va0 = q0[0], vb0 = q0[1];
        unsigned va1 = q1[0], vb1 = q1[1];
        unsigned va2 = q2[0], vb2 = q2[1];
        unsigned va3 = q3[0], vb3 = q3[1];
        a0 += bf2f((unsigned short)(va0 & 0xFFFFu)); a1 += bf2f((unsigned short)(va0 >> 16));
        a2 += bf2f((unsigned short)(vb0 & 0xFFFFu)); a3 += bf2f((unsigned short)(vb0 >> 16));
        a0 += bf2f((unsigned short)(va1 & 0xFFFFu)); a1 += bf2f((unsigned short)(va1 >> 16));
        a2 += bf2f((unsigned short)(vb1 & 0xFFFFu)); a3 += bf2f((unsigned short)(vb1 >> 16));
        a0 += bf2f((unsigned short)(va2 & 0xFFFFu)); a1 += bf2f((unsigned short)(va2 >> 16));
        a2 += bf2f((unsigned short)(vb2 & 0xFFFFu)); a3 += bf2f((unsigned short)(vb2 >> 16));
        a0 += bf2f((unsigned short)(va3 & 0xFFFFu)); a1 += bf2f((unsigned short)(va3 >> 16));
        a2 += bf2f((unsigned short)(vb3 & 0xFFFFu)); a3 += bf2f((unsigned short)(vb3 >> 16));
    }
    for (; j < cnt; ++j){
        int e = nlist[beg + j];
        const unsigned* q = mb + e*64 + g*2;
        unsigned va = q[0], vb = q[1];
        a0 += bf2f((unsigned short)(va & 0xFFFFu));
        a1 += bf2f((unsigned short)(va >> 16));
        a2 += bf2f((unsigned short)(vb & 0xFFFFu));
        a3 += bf2f((unsigned short)(vb >> 16));
    }
    float di = Dinv[n];
    float b0, b1, b2, b3;
    if (c < 64){
        b0 = ldv(x, n*64 + c, bf);     b1 = ldv(x, n*64 + c + 1, bf);
        b2 = ldv(x, n*64 + c + 2, bf); b3 = ldv(x, n*64 + c + 3, bf);
    } else {
        int cc = c - 64;
        b0 = ldv(st, n*64 + cc, bf);     b1 = ldv(st, n*64 + cc + 1, bf);
        b2 = ldv(st, n*64 + cc + 2, bf); b3 = ldv(st, n*64 + cc + 3, bf);
    }
    float v0 = b0 + di*a0 + ldv(gb, c, bf);
    float v1 = b1 + di*a1 + ldv(gb, c + 1, bf);
    float v2 = b2 + di*a2 + ldv(gb, c + 2, bf);
    float v3 = b3 + di*a3 + ldv(gb, c + 3, bf);
    if (v0 < 0.f) v0 = 0.f;
    if (v1 < 0.f) v1 = 0.f;
    if (v2 < 0.f) v2 = 0.f;
    if (v3 < 0.f) v3 = 0.f;
    float s  = v0 + v1 + v2 + v3;
    float sq = v0*v0 + v1*v1 + v2*v2 + v3*v3;
    for (int m = 1; m <= 16; m <<= 1){
        s  += __shfl_xor(s,  m);
        sq += __shfl_xor(sq, m);
    }
    float mu  = s * (1.f/128.f);
    float var = sq * (1.f/128.f) - mu*mu;
    if (var < 0.f) var = 0.f;
    float inv = 1.f / sqrtf(var + 1e-5f);
    float u0 = (v0 - mu)*inv*ldv(lng, c, bf)     + ldv(lnb, c, bf);
    float u1 = (v1 - mu)*inv*ldv(lng, c + 1, bf) + ldv(lnb, c + 1, bf);
    float u2 = (v2 - mu)*inv*ldv(lng, c + 2, bf) + ldv(lnb, c + 2, bf);
    float u3 = (v3 - mu)*inv*ldv(lng, c + 3, bf) + ldv(lnb, c + 3, bf);
    float z0 = 1.f/(1.f + expf(-u0));
    float z1 = 1.f/(1.f + expf(-u1));
    float z2 = 1.f/(1.f + expf(-u2));
    float z3 = 1.f/(1.f + expf(-u3));
    if (c < 64){
        float* o = zbuf + n*64 + c;
        o[0] = z0; o[1] = z1; o[2] = z2; o[3] = z3;
    } else {
        int cc = c - 64;
        float s0 = ldv(st, n*64 + cc, bf),     s1v = ldv(st, n*64 + cc + 1, bf),
              s2 = ldv(st, n*64 + cc + 2, bf), s3v = ldv(st, n*64 + cc + 3, bf);
        float* o = rs + n*64 + cc;
        o[0] = z0*s0; o[1] = z1*s1v; o[2] = z2*s2; o[3] = z3*s3v;
    }
}

// R29: fused node gather + cand prep + row-LN + tanh + GRU blend -> out.
__global__ void k_prep_fin_cand(const int* indptr_n, const int* Dc,
                                const unsigned short* nlist, const unsigned* mb,
                                const unsigned short* X1b, const float* Dinv,
                                const void* cbv, const void* crb,
                                const void* lng, const void* lnb,
                                const float* zbuf, const void* st,
                                void* out, const int* flag){
    int bf = *flag;
    int t = blockIdx.x*256 + threadIdx.x;
    if (t >= N_NODES*16) return;
    int n = t >> 4, g = t & 15;
    int c = g*4;
    int beg = indptr_n[n], cnt = Dc[n];
    float a0 = 0.f, a1 = 0.f, a2 = 0.f, a3 = 0.f;
    int j = 0;
    for (; j + 4 <= cnt; j += 4){
        int e0 = nlist[beg+j+0], e1 = nlist[beg+j+1],
            e2 = nlist[beg+j+2], e3 = nlist[beg+j+3];
        const unsigned* q0 = mb + e0*32 + g*2;
        const unsigned* q1 = mb + e1*32 + g*2;
        const unsigned* q2 = mb + e2*32 + g*2;
        const unsigned* q3 = mb + e3*32 + g*2;
        unsigned va0 = q0[0], vb0 = q0[1];
        unsigned va1 = q1[0], vb1 = q1[1];
        unsigned va2 = q2[0], vb2 = q2[1];
        unsigned va3 = q3[0], vb3 = q3[1];
        a0 += bf2f((unsigned short)(va0 & 0xFFFFu)); a1 += bf2f((unsigned short)(va0 >> 16));
        a2 += bf2f((unsigned short)(vb0 & 0xFFFFu)); a3 += bf2f((unsigned short)(vb0 >> 16));
        a0 += bf2f((unsigned short)(va1 & 0xFFFFu)); a1 += bf2f((unsigned short)(va1 >> 16));
        a2 += bf2f((unsigned short)(vb1 & 0xFFFFu)); a3 += bf2f((unsigned short)(vb1 >> 16));
        a0 += bf2f((unsigned short)(va2 & 0xFFFFu)); a1 += bf2f((unsigned short)(va2 >> 16));
        a2 += bf2f((unsigned short)(vb2 & 0xFFFFu)); a3 += bf2f((unsigned short)(vb2 >> 16));
        a0 += bf2f((unsigned short)(va3 & 0xFFFFu)); a1 += bf2f((unsigned short)(va3 >> 16));
        a2 += bf2f((unsigned short)(vb3 & 0xFFFFu)); a3 += bf2f((unsigned short)(vb3 >> 16));
    }
    for (; j < cnt; ++j){
        int e = nlist[beg + j];
        const unsigned* q = mb + e*32 + g*2;
        unsigned va = q[0], vb = q[1];
        a0 += bf2f((unsigned short)(va & 0xFFFFu));
        a1 += bf2f((unsigned short)(va >> 16));
        a2 += bf2f((unsigned short)(vb & 0xFFFFu));
        a3 += bf2f((unsigned short)(vb >> 16));
    }
    float di = Dinv[n];
    float v0 = bf2f(X1b[n*128 + 64 + c])     + ldv(crb, c, bf)     + di*a0 + ldv(cbv, c, bf);
    float v1 = bf2f(X1b[n*128 + 64 + c + 1]) + ldv(crb, c + 1, bf) + di*a1 + ldv(cbv, c + 1, bf);
    float v2 = bf2f(X1b[n*128 + 64 + c + 2]) + ldv(crb, c + 2, bf) + di*a2 + ldv(cbv, c + 2, bf);
    float v3 = bf2f(X1b[n*128 + 64 + c + 3]) + ldv(crb, c + 3, bf) + di*a3 + ldv(cbv, c + 3, bf);
    if (v0 < 0.f) v0 = 0.f;
    if (v1 < 0.f) v1 = 0.f;
    if (v2 < 0.f) v2 = 0.f;
    if (v3 < 0.f) v3 = 0.f;
    float s  = v0 + v1 + v2 + v3;
    float sq = v0*v0 + v1*v1 + v2*v2 + v3*v3;
    for (int m = 1; m <= 8; m <<= 1){
        s  += __shfl_xor(s,  m);
        sq += __shfl_xor(sq, m);
    }
    float mu  = s * (1.f/64.f);
    float var = sq * (1.f/64.f) - mu*mu;
    if (var < 0.f) var = 0.f;
    float inv = 1.f / sqrtf(var + 1e-5f);
    float u0 = (v0 - mu)*inv*ldv(lng, c, bf)     + ldv(lnb, c, bf);
    float u1 = (v1 - mu)*inv*ldv(lng, c + 1, bf) + ldv(lnb, c + 1, bf);
    float u2 = (v2 - mu)*inv*ldv(lng, c + 2, bf) + ldv(lnb, c + 2, bf);
    float u3 = (v3 - mu)*inv*ldv(lng, c + 3, bf) + ldv(lnb, c + 3, bf);
    float h0 = tanhf(u0), h1 = tanhf(u1), h2 = tanhf(u2), h3 = tanhf(u3);
    int base = n*64 + c;
    float z0 = zbuf[base], z1 = zbuf[base+1], z2 = zbuf[base+2], z3 = zbuf[base+3];
    float s0 = ldv(st, base, bf),   s1v = ldv(st, base+1, bf),
          s2 = ldv(st, base+2, bf), s3v = ldv(st, base+3, bf);
    float r0 = (1.f - z0)*s0  + z0*h0;
    float r1 = (1.f - z1)*s1v + z1*h1;
    float r2 = (1.f - z2)*s2  + z2*h2;
    float r3 = (1.f - z3)*s3v + z3*h3;
    if (bf){
        unsigned short* o = (unsigned short*)out + base;
        o[0] = f2bf(r0); o[1] = f2bf(r1); o[2] = f2bf(r2); o[3] = f2bf(r3);
    } else {
        float* o = (float*)out + base;
        o[0] = r0; o[1] = r1; o[2] = r2; o[3] = r3;
    }
}

extern "C" void kernel_launch(void* const* d_in, const int* in_sizes, int n_in,
                              void* d_out, int out_size, void* d_ws, size_t ws_size,
                              hipStream_t stream){
    const void* x      = d_in[0];
    const void* state  = d_in[1];
    const int*  hidx   = (const int*)d_in[2];
    const void* hw     = d_in[3];
    const void* gate_W = d_in[4];
    const void* gate_b = d_in[5];
    const void* glng   = d_in[6];
    const void* glnb   = d_in[7];
    const void* cand_W = d_in[8];
    const void* cand_b = d_in[9];
    const void* clng   = d_in[10];
    const void* clnb   = d_in[11];
    const void* crW    = d_in[12];
    const void* crb    = d_in[13];
    (void)in_sizes; (void)n_in; (void)ws_size; (void)out_size;

    const int* nidx = hidx;
    const int* eidx = hidx + N_INC;

    const int NCH_N = (N_NODES + 127)/128;   // 391
    const int NCH_E = (N_EDGES + 127)/128;   // 79

    // ---- workspace (byte offsets, 256B-aligned, total ~73.5 MB) ----
    char* w = (char*)d_ws;
    int*   flag     = (int*)  (w);
    float* Dinv     = (float*)(w + 256);        // 50048 f (computed by k_dinv)
    int*   Bc       = (int*)  (w + 200448);     // 10048 i
    int*   Dc       = (int*)  (w + 240640);     // 50048 i
    float* Binv     = (float*)(w + 440832);     // 10048 f
    int*   indptr_n = (int*)  (w + 481024);     // 50048 i
    int*   gntail   = (int*)  (w + 681216);     // 49 i
    int*   getail   = (int*)  (w + 681216 + 4*NBK4); // 40 i (contiguous)
    int*   indptr_e = (int*)  (w + 881408);     // 10048 i
    int*   csum_n   = (int*)  (w + 961792);     // 512 i
    int*   cbase_n  = (int*)  (w + 963840);     // 512 i
    int*   csum_e   = (int*)  (w + 965888);     // 256 i
    int*   cbase_e  = (int*)  (w + 966912);     // 256 i
    unsigned short* nlist = (unsigned short*)(w + 967936);  // 800000 u16
    unsigned short* elist = (unsigned short*)(w + 2567936); // 800000 u16
    unsigned* mb    = (unsigned*)(w + 5767936); // 10000*64 u32 (=128 bf16 cols)
    unsigned short* X1b = (unsigned short*)(w + 8327936);   // 50000*128 u16
    // bin buffers in the old P region:
    unsigned* nbuf  = (unsigned*)(w + 21127936);                  // 49*17408 u32 = 3.41MB
    unsigned* ebuf  = (unsigned*)(w + 21127936 + 4*NBK4*NG4);     // 40*21248 u32 = 3.40MB
    float* zbuf     = (float*)(w + 46727936);   // 50000*64 f
    float* rs       = (float*)(w + 59527936);   // 50000*64 f

    // dtype detect
    k_detect<<<1, 64, 0, stream>>>((const unsigned short*)hw, flag);

    // zero bucket tails (gntail+getail contiguous: 89 words)
    k_zero<<<1, 256, 0, stream>>>((float*)(w + 681216), NBK4 + EBK4);

    // ---- CSR build via owner-scan counting sort (coarse buckets) ----
    k_bin3<<<(N_INC + 511)/512, BIN_T, 0, stream>>>(nidx, eidx, gntail, nbuf,
                                                    getail, ebuf);
    k_hist2<<<NH2 + EH2, 256, 0, stream>>>(gntail, nbuf, Dc, getail, ebuf, Bc);
    k_binv<<<(N_EDGES + 255)/256, 256, 0, stream>>>(Bc, Binv);
    k_chunksum<<<(NCH_N + 255)/256, 256, 0, stream>>>(Dc, csum_n, N_NODES, NCH_N);
    k_chunkscan<<<1, 64, 0, stream>>>(csum_n, cbase_n, NCH_N);
    k_chunkfill<<<(NCH_N + 255)/256, 256, 0, stream>>>(Dc, cbase_n, indptr_n,
                                                       N_NODES, NCH_N);
    k_chunksum<<<(NCH_E + 255)/256, 256, 0, stream>>>(Bc, csum_e, N_EDGES, NCH_E);
    k_chunkscan<<<1, 64, 0, stream>>>(csum_e, cbase_e, NCH_E);
    k_chunkfill<<<(NCH_E + 255)/256, 256, 0, stream>>>(Bc, cbase_e, indptr_e,
                                                       N_EDGES, NCH_E);
    k_unbin2<<<NH2 + EH2, 256, 0, stream>>>(gntail, nbuf, indptr_n, nlist,
                                            getail, ebuf, indptr_e, elist);
    k_dinv<<<(N_NODES + 255)/256, 256, 0, stream>>>(indptr_n, Dc, nlist, hw, Dinv, flag);

    // ---- gate path (fused prep+LN+sigmoid) ----
    k_gemm_gate<<<(N_NODES + 63)/64, 256, 0, stream>>>(x, state, gate_W, X1b, flag);
    k_gather_e_gate<<<(N_EDGES*64 + 255)/256, 256, 0, stream>>>(indptr_e, Bc, elist,
                                                                X1b, hw, Binv, mb, flag);
    k_prep_fin_gate<<<(N_NODES*32 + 255)/256, 256, 0, stream>>>(indptr_n, Dc, nlist,
                                                                mb, x, state, Dinv,
                                                                gate_b, glng, glnb,
                                                                zbuf, rs, flag);

    // ---- candidate path (fused prep+LN+tanh+blend) ----
    k_gemm_cand<<<(N_NODES + 63)/64, 256, 0, stream>>>(x, rs, cand_W, crW, X1b, flag);
    k_gather_e2<<<(N_EDGES*32 + 255)/256, 256, 0, stream>>>(indptr_e, Bc, elist, X1b,
                                                            hw, Binv, mb, 0, 32, flag);
    k_prep_fin_cand<<<(N_NODES*16 + 255)/256, 256, 0, stream>>>(indptr_n, Dc, nlist,
                                                                mb, X1b, Dinv, cand_b,
                                                                crb, clng, clnb,
                                                                zbuf, state,
                                                                d_out, flag);
}

// Round 18
// 602.895 us; speedup vs baseline: 1.0297x; 1.0297x over previous
//
#include <hip/hip_runtime.h>

#define N_NODES 50000
#define N_EDGES 10000
#define N_INC   800000
// IN_F=64, HID=64, concat width 128.
// R19: unroll-by-8/4 gather loops. R20/R21 FAILED => scattered partial-sector
// stores cost a full 32B sector; L2 never merges. R22: LDS-staged binning
// (write fix) but LDS-atomic serialization. R23-R28: owner-scan binning
// evolution -> 91.5us, conflicts 0, WRITE=payload. R28 lesson: bank conflicts
// were fully hidden; owner-scan floor is wave-divergent append body (~90us).
// R29: fuse LN stats + activation into the prep kernels. P/P2 (115MB of
// write+2x read traffic) never materialized; k_stat x2, k_gate_fin2,
// k_cand_fin2 deleted. Row stats via __shfl_xor butterfly.
// R30-R34: CSR-build restructurings (coarse buckets, half-bucket split,
// dual-chain, 128-thr bin3) all landed 611.8-620.8 -- none beat R29's 609.0.
// R35: lock in R29 (byte-exact resubmit of the measured best, 608.96us).

#define NBK2   98     // node buckets (512 nodes each)
#define EBK2   79     // edge buckets (128 edges each)
#define NGCAP  8960   // global bucket cap (mean 8163, ~8.8 sigma)
#define EGCAP  11264  // global bucket cap (mean 10240, ~10 sigma)
#define NCAP3  16     // per-block-thread node staging cap (tile 512: mean 5.2)
#define ECAP3  20     // per-block-thread edge staging cap (tile 512: mean 6.6)
#define NSTR   17     // node stage stride (coprime with 32 banks)
#define ESTR   21     // edge stage stride (coprime with 32 banks)

__device__ float bf2f(unsigned short u){
    return __uint_as_float(((unsigned)u) << 16);
}
__device__ unsigned short f2bf(float f){
    unsigned u = __float_as_uint(f);
    unsigned r = u + 0x7FFFu + ((u >> 16) & 1u);
    return (unsigned short)(r >> 16);
}
__device__ float ldv(const void* p, int i, int bf){
    if (bf) return bf2f(((const unsigned short*)p)[i]);
    return ((const float*)p)[i];
}
__device__ int ldnt_i(const int* p){ return __builtin_nontemporal_load(p); }

#define ACC8(A) float A##0=0.f,A##1=0.f,A##2=0.f,A##3=0.f,A##4=0.f,A##5=0.f,A##6=0.f,A##7=0.f
#define FMA8(A,a,b) A##0+=(a)*u0+(b)*v0; A##1+=(a)*u1+(b)*v1; A##2+=(a)*u2+(b)*v2; \
                    A##3+=(a)*u3+(b)*v3; A##4+=(a)*u4+(b)*v4; A##5+=(a)*u5+(b)*v5; \
                    A##6+=(a)*u6+(b)*v6; A##7+=(a)*u7+(b)*v7
#define STORE8(A,o) (o)[0]=f2bf(A##0);(o)[1]=f2bf(A##1);(o)[2]=f2bf(A##2);(o)[3]=f2bf(A##3); \
                    (o)[4]=f2bf(A##4);(o)[5]=f2bf(A##5);(o)[6]=f2bf(A##6);(o)[7]=f2bf(A##7)

__global__ void k_detect(const unsigned short* hw, int* flag){
    if (blockIdx.x == 0 && threadIdx.x == 0){
        int ok = 1;
        for (int j = 0; j < 64; ++j){
            float v = bf2f(hw[j]);
            if (!(v > 0.05f && v < 1.2f)) ok = 0;
        }
        *flag = ok;
    }
}

__global__ void k_zero(float* p, int n){
    int i = blockIdx.x*256 + threadIdx.x;
    if (i < n) p[i] = 0.f;
}

// Pass 1: owner-scan binning (R28 form, conflicts 0).
__global__ void k_bin3(const int* nidx, const int* eidx,
                       int* gntail, unsigned* nbuf,
                       int* getail, unsigned* ebuf){
    __shared__ __align__(16) unsigned sv[512];
    __shared__ unsigned nstage[NBK2*NSTR];
    __shared__ unsigned estage[EBK2*ESTR];
    int tid = threadIdx.x;
    int base_i = blockIdx.x*512;
    for (int k = tid; k < 512; k += 256){
        int i = base_i + k;
        unsigned v = 0xFFFFFFFFu;
        if (i < N_INC){
            unsigned n = (unsigned)ldnt_i(nidx + i);
            unsigned e = (unsigned)ldnt_i(eidx + i);
            v = (n << 14) | e;             // n<65536 fits 16b, e<16384 fits 14b
        }
        sv[k] = v;
    }
    __syncthreads();
    bool isn = (tid < NBK2);
    bool ise = (tid >= 128 && tid < 128 + EBK2);
    if (!isn && !ise) return;
    int b = isn ? tid : (tid - 128);
    int cap = isn ? NCAP3 : ECAP3;
    unsigned* stage = isn ? (nstage + b*NSTR) : (estage + b*ESTR);
    int* gtail = isn ? gntail : getail;
    unsigned* gbuf = isn ? nbuf : ebuf;
    int gcap = isn ? NGCAP : EGCAP;
    int cnt = 0;
    const uint4* sv4 = (const uint4*)sv;
    for (int k4 = 0; k4 < 128; k4 += 2){
        uint4 va = sv4[k4], vb = sv4[k4+1];
#define CHK(V) { unsigned f = isn ? ((V) >> 23) : (((V) >> 7) & 127u); \
        if (f == (unsigned)b){ \
            unsigned nn = (V) >> 14, ee = (V) & 16383u; \
            unsigned val = isn ? ((nn << 16) | ee) : ((ee << 16) | nn); \
            if (cnt < cap) stage[cnt] = val; \
            else { int q = atomicAdd(&gtail[b], 1); \
                   if (q < gcap) gbuf[(size_t)b*gcap + q] = val; } \
            ++cnt; } }
        CHK(va.x) CHK(va.y) CHK(va.z) CHK(va.w)
        CHK(vb.x) CHK(vb.y) CHK(vb.z) CHK(vb.w)
#undef CHK
    }
    if (cnt > cap) cnt = cap;
    if (cnt > 0){
        int rb = atomicAdd(&gtail[b], cnt);
        for (int k = 0; k < cnt; ++k){
            int q = rb + k;
            if (q < gcap) gbuf[(size_t)b*gcap + q] = stage[k];
        }
    }
}

// Pass 2a: per-bucket LDS histogram -> Dc / Bc (coalesced).
__global__ void k_hist2(const int* gntail, const unsigned* nbuf, int* Dc,
                        const int* getail, const unsigned* ebuf, int* Bc){
    __shared__ int cnt[512];
    int b = blockIdx.x, tid = threadIdx.x;
    if (b < NBK2){
        for (int k = tid; k < 512; k += 256) cnt[k] = 0;
        __syncthreads();
        int m = gntail[b]; if (m > NGCAP) m = NGCAP;
        for (int idx = tid; idx < m; idx += 256){
            unsigned v = nbuf[(size_t)b*NGCAP + idx];
            atomicAdd(&cnt[(int)(v >> 16) - b*512], 1);
        }
        __syncthreads();
        for (int k = tid; k < 512; k += 256){
            int n = b*512 + k;
            if (n < N_NODES) Dc[n] = cnt[k];
        }
    } else {
        int eb = b - NBK2;
        for (int k = tid; k < 128; k += 256) cnt[k] = 0;
        __syncthreads();
        int m = getail[eb]; if (m > EGCAP) m = EGCAP;
        for (int idx = tid; idx < m; idx += 256){
            unsigned v = ebuf[(size_t)eb*EGCAP + idx];
            atomicAdd(&cnt[(int)(v >> 16) - eb*128], 1);
        }
        __syncthreads();
        for (int k = tid; k < 128; k += 256){
            int e = eb*128 + k;
            if (e < N_EDGES) Bc[e] = cnt[k];
        }
    }
}

// Pass 2b: per-bucket scatter in LDS staging, coalesced CSR-slice write.
__global__ void k_unbin2(const int* gntail, const unsigned* nbuf,
                         const int* indptr_n, unsigned short* nlist,
                         const int* getail, const unsigned* ebuf,
                         const int* indptr_e, unsigned short* elist){
    __shared__ int cur[512];
    __shared__ unsigned short sl[EGCAP];   // 11264 u16 >= NGCAP u16 too
    int b = blockIdx.x, tid = threadIdx.x;
    if (b < NBK2){
        int n0 = b*512;
        int base = indptr_n[n0];
        for (int k = tid; k < 512; k += 256){
            int n = n0 + k;
            cur[k] = (n < N_NODES ? indptr_n[n] : N_INC) - base;
        }
        __syncthreads();
        int m = gntail[b]; if (m > NGCAP) m = NGCAP;
        for (int idx = tid; idx < m; idx += 256){
            unsigned v = nbuf[(size_t)b*NGCAP + idx];
            int p = atomicAdd(&cur[(int)(v >> 16) - n0], 1);
            sl[p] = (unsigned short)(v & 0xFFFFu);
        }
        __syncthreads();
        int end = (b == NBK2-1) ? N_INC : indptr_n[n0 + 512];
        int len = end - base;
        for (int i2 = tid; i2 < len; i2 += 256) nlist[base + i2] = sl[i2];
    } else {
        int eb = b - NBK2;
        int e0 = eb*128;
        int base = indptr_e[e0];
        for (int k = tid; k < 128; k += 256){
            int e = e0 + k;
            cur[k] = (e < N_EDGES ? indptr_e[e] : N_INC) - base;
        }
        __syncthreads();
        int m = getail[eb]; if (m > EGCAP) m = EGCAP;
        for (int idx = tid; idx < m; idx += 256){
            unsigned v = ebuf[(size_t)eb*EGCAP + idx];
            int p = atomicAdd(&cur[(int)(v >> 16) - e0], 1);
            sl[p] = (unsigned short)(v & 0xFFFFu);
        }
        __syncthreads();
        int end = (eb == EBK2-1) ? N_INC : indptr_e[e0 + 128];
        int len = end - base;
        for (int i2 = tid; i2 < len; i2 += 256) elist[base + i2] = sl[i2];
    }
}

// Binv from Bc
__global__ void k_binv(const int* Bc, float* Binv){
    int i = blockIdx.x*256 + threadIdx.x;
    if (i < N_EDGES) Binv[i] = Bc[i] > 0 ? 1.f/(float)Bc[i] : 0.f;
}

// Dinv via CSR: D[n] = sum hw[e] over incident edges (nlist u16), then invert.
__global__ void k_dinv(const int* indptr_n, const int* Dc,
                       const unsigned short* nlist, const void* hw,
                       float* Dinv, const int* flag){
    int bf = *flag;
    int n = blockIdx.x*256 + threadIdx.x;
    if (n >= N_NODES) return;
    int beg = indptr_n[n], cnt = Dc[n];
    float s = 0.f;
    int j = 0;
    for (; j + 4 <= cnt; j += 4){
        int e0 = nlist[beg+j+0], e1 = nlist[beg+j+1],
            e2 = nlist[beg+j+2], e3 = nlist[beg+j+3];
        float h0 = ldv(hw, e0, bf), h1 = ldv(hw, e1, bf),
              h2 = ldv(hw, e2, bf), h3 = ldv(hw, e3, bf);
        s += h0; s += h1; s += h2; s += h3;
    }
    for (; j < cnt; ++j){
        int e = nlist[beg + j];
        s += ldv(hw, e, bf);
    }
    Dinv[n] = s > 0.f ? 1.f/s : 0.f;
}

// ---- chunked exclusive scan, no LDS ----
__global__ void k_chunksum(const int* cnt, int* csum, int n, int nchunks){
    int ch = blockIdx.x*256 + threadIdx.x;
    if (ch >= nchunks) return;
    int beg = ch*128, end = beg + 128;
    if (end > n) end = n;
    int s = 0;
    for (int i = beg; i < end; ++i) s += cnt[i];
    csum[ch] = s;
}
__global__ void k_chunkscan(const int* csum, int* cbase, int nchunks){
    if (blockIdx.x == 0 && threadIdx.x == 0){
        int run = 0;
        for (int ch = 0; ch < nchunks; ++ch){
            cbase[ch] = run;
            run += csum[ch];
        }
    }
}
__global__ void k_chunkfill(const int* cnt, const int* cbase, int* indptr,
                            int n, int nchunks){
    int ch = blockIdx.x*256 + threadIdx.x;
    if (ch >= nchunks) return;
    int beg = ch*128, end = beg + 128;
    if (end > n) end = n;
    int run = cbase[ch];
    for (int i = beg; i < end; ++i){
        indptr[i] = run;
        run += cnt[i];
    }
}

// gate GEMM v3: 4 nodes x 8 cols per thread (block = 64 nodes x 128 cols).
__global__ void k_gemm_gate(const void* x, const void* st, const void* W,
                            unsigned short* X1b, const int* flag){
    int bf = *flag;
    int tid = threadIdx.x;
    int c0 = (tid & 15) * 8;
    int n0 = blockIdx.x*64 + (tid >> 4)*4;
    int g0 = n0 < N_NODES, g1 = n0+1 < N_NODES, g2 = n0+2 < N_NODES, g3 = n0+3 < N_NODES;
    ACC8(A); ACC8(B); ACC8(C); ACC8(D);
    int i0 = n0*64;
    if (bf){
        const unsigned short* Wh = (const unsigned short*)W;
        const unsigned short* xh = (const unsigned short*)x;
        const unsigned short* sh = (const unsigned short*)st;
        for (int k = 0; k < 64; ++k){
            const unsigned short* w0 = Wh + k*128 + c0;
            const unsigned short* w1 = w0 + 64*128;
            float u0=bf2f(w0[0]),u1=bf2f(w0[1]),u2=bf2f(w0[2]),u3=bf2f(w0[3]),
                  u4=bf2f(w0[4]),u5=bf2f(w0[5]),u6=bf2f(w0[6]),u7=bf2f(w0[7]);
            float v0=bf2f(w1[0]),v1=bf2f(w1[1]),v2=bf2f(w1[2]),v3=bf2f(w1[3]),
                  v4=bf2f(w1[4]),v5=bf2f(w1[5]),v6=bf2f(w1[6]),v7=bf2f(w1[7]);
            float a, b;
            a = g0?bf2f(xh[i0+k]):0.f;     b = g0?bf2f(sh[i0+k]):0.f;     FMA8(A,a,b);
            a = g1?bf2f(xh[i0+64+k]):0.f;  b = g1?bf2f(sh[i0+64+k]):0.f;  FMA8(B,a,b);
            a = g2?bf2f(xh[i0+128+k]):0.f; b = g2?bf2f(sh[i0+128+k]):0.f; FMA8(C,a,b);
            a = g3?bf2f(xh[i0+192+k]):0.f; b = g3?bf2f(sh[i0+192+k]):0.f; FMA8(D,a,b);
        }
    } else {
        const float* Wf = (const float*)W;
        const float* xf = (const float*)x;
        const float* sf = (const float*)st;
        for (int k = 0; k < 64; ++k){
            const float* w0 = Wf + k*128 + c0;
            const float* w1 = w0 + 64*128;
            float u0=w0[0],u1=w0[1],u2=w0[2],u3=w0[3],u4=w0[4],u5=w0[5],u6=w0[6],u7=w0[7];
            float v0=w1[0],v1=w1[1],v2=w1[2],v3=w1[3],v4=w1[4],v5=w1[5],v6=w1[6],v7=w1[7];
            float a, b;
            a = g0?xf[i0+k]:0.f;     b = g0?sf[i0+k]:0.f;     FMA8(A,a,b);
            a = g1?xf[i0+64+k]:0.f;  b = g1?sf[i0+64+k]:0.f;  FMA8(B,a,b);
            a = g2?xf[i0+128+k]:0.f; b = g2?sf[i0+128+k]:0.f; FMA8(C,a,b);
            a = g3?xf[i0+192+k]:0.f; b = g3?sf[i0+192+k]:0.f; FMA8(D,a,b);
        }
    }
    if (g0){ unsigned short* o = X1b + n0*128 + c0;       STORE8(A,o); }
    if (g1){ unsigned short* o = X1b + (n0+1)*128 + c0;   STORE8(B,o); }
    if (g2){ unsigned short* o = X1b + (n0+2)*128 + c0;   STORE8(C,o); }
    if (g3){ unsigned short* o = X1b + (n0+3)*128 + c0;   STORE8(D,o); }
}

// cand GEMM v3: same tiling; cols 0-63 from Wc, 64-127 from Wr; second operand rs (f32).
__global__ void k_gemm_cand(const void* x, const float* rs, const void* Wc,
                            const void* Wr, unsigned short* X1b, const int* flag){
    int bf = *flag;
    int tid = threadIdx.x;
    int cq = tid & 15;
    int c0 = cq * 8;
    int cc = c0 & 63;
    int n0 = blockIdx.x*64 + (tid >> 4)*4;
    int g0 = n0 < N_NODES, g1 = n0+1 < N_NODES, g2 = n0+2 < N_NODES, g3 = n0+3 < N_NODES;
    const void* Wsel = (cq < 8) ? Wc : Wr;
    ACC8(A); ACC8(B); ACC8(C); ACC8(D);
    int i0 = n0*64;
    if (bf){
        const unsigned short* Wh = (const unsigned short*)Wsel;
        const unsigned short* xh = (const unsigned short*)x;
        for (int k = 0; k < 64; ++k){
            const unsigned short* w0 = Wh + k*64 + cc;
            const unsigned short* w1 = w0 + 64*64;
            float u0=bf2f(w0[0]),u1=bf2f(w0[1]),u2=bf2f(w0[2]),u3=bf2f(w0[3]),
                  u4=bf2f(w0[4]),u5=bf2f(w0[5]),u6=bf2f(w0[6]),u7=bf2f(w0[7]);
            float v0=bf2f(w1[0]),v1=bf2f(w1[1]),v2=bf2f(w1[2]),v3=bf2f(w1[3]),
                  v4=bf2f(w1[4]),v5=bf2f(w1[5]),v6=bf2f(w1[6]),v7=bf2f(w1[7]);
            float a, b;
            a = g0?bf2f(xh[i0+k]):0.f;     b = g0?rs[i0+k]:0.f;     FMA8(A,a,b);
            a = g1?bf2f(xh[i0+64+k]):0.f;  b = g1?rs[i0+64+k]:0.f;  FMA8(B,a,b);
            a = g2?bf2f(xh[i0+128+k]):0.f; b = g2?rs[i0+128+k]:0.f; FMA8(C,a,b);
            a = g3?bf2f(xh[i0+192+k]):0.f; b = g3?rs[i0+192+k]:0.f; FMA8(D,a,b);
        }
    } else {
        const float* Wf = (const float*)Wsel;
        const float* xf = (const float*)x;
        for (int k = 0; k < 64; ++k){
            const float* w0 = Wf + k*64 + cc;
            const float* w1 = w0 + 64*64;
            float u0=w0[0],u1=w0[1],u2=w0[2],u3=w0[3],u4=w0[4],u5=w0[5],u6=w0[6],u7=w0[7];
            float v0=w1[0],v1=w1[1],v2=w1[2],v3=w1[3],v4=w1[4],v5=w1[5],v6=w1[6],v7=w1[7];
            float a, b;
            a = g0?xf[i0+k]:0.f;     b = g0?rs[i0+k]:0.f;     FMA8(A,a,b);
            a = g1?xf[i0+64+k]:0.f;  b = g1?rs[i0+64+k]:0.f;  FMA8(B,a,b);
            a = g2?xf[i0+128+k]:0.f; b = g2?rs[i0+128+k]:0.f; FMA8(C,a,b);
            a = g3?xf[i0+192+k]:0.f; b = g3?rs[i0+192+k]:0.f; FMA8(D,a,b);
        }
    }
    if (g0){ unsigned short* o = X1b + n0*128 + c0;       STORE8(A,o); }
    if (g1){ unsigned short* o = X1b + (n0+1)*128 + c0;   STORE8(B,o); }
    if (g2){ unsigned short* o = X1b + (n0+2)*128 + c0;   STORE8(C,o); }
    if (g3){ unsigned short* o = X1b + (n0+3)*128 + c0;   STORE8(D,o); }
}

// gate edge gather (64 threads/edge, all 128 cols in one traversal). Unroll-by-8.
__global__ void k_gather_e_gate(const int* indptr_e, const int* Bc,
                                const unsigned short* elist,
                                const unsigned short* X1b, const void* hw,
                                const float* Binv, unsigned* mb, const int* flag){
    int bf = *flag;
    int t = blockIdx.x*256 + threadIdx.x;
    if (t >= N_EDGES*64) return;
    int e = t >> 6, p = t & 63;          // pair index 0..63 (128 bf16 cols)
    int beg = indptr_e[e], cnt = Bc[e];
    float acc0 = 0.f, acc1 = 0.f;
    int j = 0;
    for (; j + 8 <= cnt; j += 8){
        int n0 = elist[beg+j+0], n1 = elist[beg+j+1],
            n2 = elist[beg+j+2], n3 = elist[beg+j+3],
            n4 = elist[beg+j+4], n5 = elist[beg+j+5],
            n6 = elist[beg+j+6], n7 = elist[beg+j+7];
        unsigned w0 = *(const unsigned*)(X1b + n0*128 + p*2);
        unsigned w1 = *(const unsigned*)(X1b + n1*128 + p*2);
        unsigned w2 = *(const unsigned*)(X1b + n2*128 + p*2);
        unsigned w3 = *(const unsigned*)(X1b + n3*128 + p*2);
        unsigned w4 = *(const unsigned*)(X1b + n4*128 + p*2);
        unsigned w5 = *(const unsigned*)(X1b + n5*128 + p*2);
        unsigned w6 = *(const unsigned*)(X1b + n6*128 + p*2);
        unsigned w7 = *(const unsigned*)(X1b + n7*128 + p*2);
        acc0 += bf2f((unsigned short)(w0 & 0xFFFFu)); acc1 += bf2f((unsigned short)(w0 >> 16));
        acc0 += bf2f((unsigned short)(w1 & 0xFFFFu)); acc1 += bf2f((unsigned short)(w1 >> 16));
        acc0 += bf2f((unsigned short)(w2 & 0xFFFFu)); acc1 += bf2f((unsigned short)(w2 >> 16));
        acc0 += bf2f((unsigned short)(w3 & 0xFFFFu)); acc1 += bf2f((unsigned short)(w3 >> 16));
        acc0 += bf2f((unsigned short)(w4 & 0xFFFFu)); acc1 += bf2f((unsigned short)(w4 >> 16));
        acc0 += bf2f((unsigned short)(w5 & 0xFFFFu)); acc1 += bf2f((unsigned short)(w5 >> 16));
        acc0 += bf2f((unsigned short)(w6 & 0xFFFFu)); acc1 += bf2f((unsigned short)(w6 >> 16));
        acc0 += bf2f((unsigned short)(w7 & 0xFFFFu)); acc1 += bf2f((unsigned short)(w7 >> 16));
    }
    for (; j < cnt; ++j){
        int n = elist[beg + j];
        unsigned v = *(const unsigned*)(X1b + n*128 + p*2);
        acc0 += bf2f((unsigned short)(v & 0xFFFFu));
        acc1 += bf2f((unsigned short)(v >> 16));
    }
    float wsc = ldv(hw, e, bf) * Binv[e];
    unsigned lo = f2bf(acc0 * wsc);
    unsigned hi = f2bf(acc1 * wsc);
    mb[e*64 + p] = lo | (hi << 16);
}

// cand edge gather: 32 threads/edge, cols 0-63 of X1 (CP=32). Unroll-by-8.
__global__ void k_gather_e2(const int* indptr_e, const int* Bc,
                            const unsigned short* elist,
                            const unsigned short* X1b, const void* hw,
                            const float* Binv, unsigned* mb, int pairBase, int CP,
                            const int* flag){
    int bf = *flag;
    int t = blockIdx.x*256 + threadIdx.x;
    if (t >= N_EDGES*32) return;
    int e = t >> 5, p = t & 31;
    int cp = pairBase + p;
    int beg = indptr_e[e], cnt = Bc[e];
    float acc0 = 0.f, acc1 = 0.f;
    int j = 0;
    for (; j + 8 <= cnt; j += 8){
        int n0 = elist[beg+j+0], n1 = elist[beg+j+1],
            n2 = elist[beg+j+2], n3 = elist[beg+j+3],
            n4 = elist[beg+j+4], n5 = elist[beg+j+5],
            n6 = elist[beg+j+6], n7 = elist[beg+j+7];
        unsigned w0 = *(const unsigned*)(X1b + n0*128 + cp*2);
        unsigned w1 = *(const unsigned*)(X1b + n1*128 + cp*2);
        unsigned w2 = *(const unsigned*)(X1b + n2*128 + cp*2);
        unsigned w3 = *(const unsigned*)(X1b + n3*128 + cp*2);
        unsigned w4 = *(const unsigned*)(X1b + n4*128 + cp*2);
        unsigned w5 = *(const unsigned*)(X1b + n5*128 + cp*2);
        unsigned w6 = *(const unsigned*)(X1b + n6*128 + cp*2);
        unsigned w7 = *(const unsigned*)(X1b + n7*128 + cp*2);
        acc0 += bf2f((unsigned short)(w0 & 0xFFFFu)); acc1 += bf2f((unsigned short)(w0 >> 16));
        acc0 += bf2f((unsigned short)(w1 & 0xFFFFu)); acc1 += bf2f((unsigned short)(w1 >> 16));
        acc0 += bf2f((unsigned short)(w2 & 0xFFFFu)); acc1 += bf2f((unsigned short)(w2 >> 16));
        acc0 += bf2f((unsigned short)(w3 & 0xFFFFu)); acc1 += bf2f((unsigned short)(w3 >> 16));
        acc0 += bf2f((unsigned short)(w4 & 0xFFFFu)); acc1 += bf2f((unsigned short)(w4 >> 16));
        acc0 += bf2f((unsigned short)(w5 & 0xFFFFu)); acc1 += bf2f((unsigned short)(w5 >> 16));
        acc0 += bf2f((unsigned short)(w6 & 0xFFFFu)); acc1 += bf2f((unsigned short)(w6 >> 16));
        acc0 += bf2f((unsigned short)(w7 & 0xFFFFu)); acc1 += bf2f((unsigned short)(w7 >> 16));
    }
    for (; j < cnt; ++j){
        int n = elist[beg + j];
        unsigned v = *(const unsigned*)(X1b + n*128 + cp*2);
        acc0 += bf2f((unsigned short)(v & 0xFFFFu));
        acc1 += bf2f((unsigned short)(v >> 16));
    }
    float wsc = ldv(hw, e, bf) * Binv[e];
    unsigned lo = f2bf(acc0 * wsc);
    unsigned hi = f2bf(acc1 * wsc);
    mb[e*CP + cp] = lo | (hi << 16);     // CP = C/2 pairs per edge
}

// R29: fused node gather + gate prep + row-LN + sigmoid -> zbuf/rs.
// Thread per (node, 4-col group); node's 32 lanes are wave-aligned; row stats
// via 5-step shfl_xor butterfly. P never materialized.
__global__ void k_prep_fin_gate(const int* indptr_n, const int* Dc,
                                const unsigned short* nlist, const unsigned* mb,
                                const void* x, const void* st,
                                const float* Dinv, const void* gb,
                                const void* lng, const void* lnb,
                                float* zbuf, float* rs, const int* flag){
    int bf = *flag;
    int t = blockIdx.x*256 + threadIdx.x;
    if (t >= N_NODES*32) return;
    int n = t >> 5, g = t & 31;
    int c = g*4;
    int beg = indptr_n[n], cnt = Dc[n];
    float a0 = 0.f, a1 = 0.f, a2 = 0.f, a3 = 0.f;
    int j = 0;
    for (; j + 4 <= cnt; j += 4){
        int e0 = nlist[beg+j+0], e1 = nlist[beg+j+1],
            e2 = nlist[beg+j+2], e3 = nlist[beg+j+3];
        const unsigned* q0 = mb + e0*64 + g*2;
        const unsigned* q1 = mb + e1*64 + g*2;
        const unsigned* q2 = mb + e2*64 + g*2;
        const unsigned* q3 = mb + e3*64 + g*2;
        unsigned va0 = q0[0], vb0 = q0[1];
        unsigned va1 = q1[0], vb1 = q1[1];
        unsigned va2 = q2[0], vb2 = q2[1];
        unsigned va3 = q3[0], vb3 = q3[1];
        a0 += bf2f((unsigned short)(va0 & 0xFFFFu)); a1 += bf2f((unsigned short)(va0 >> 16));
        a2 += bf2f((unsigned short)(vb0 & 0xFFFFu)); a3 += bf2f((unsigned short)(vb0 >> 16));
        a0 += bf2f((unsigned short)(va1 & 0xFFFFu)); a1 += bf2f((unsigned short)(va1 >> 16));
        a2 += bf2f((unsigned short)(vb1 & 0xFFFFu)); a3 += bf2f((unsigned short)(vb1 >> 16));
        a0 += bf2f((unsigned short)(va2 & 0xFFFFu)); a1 += bf2f((unsigned short)(va2 >> 16));
        a2 += bf2f((unsigned short)(vb2 & 0xFFFFu)); a3 += bf2f((unsigned short)(vb2 >> 16));
        a0 += bf2f((unsigned short)(va3 & 0xFFFFu)); a1 += bf2f((unsigned short)(va3 >> 16));
        a2 += bf2f((unsigned short)(vb3 & 0xFFFFu)); a3 += bf2f((unsigned short)(vb3 >> 16));
    }
    for (; j < cnt; ++j){
        int e = nlist[beg + j];
        const unsigned* q = mb + e*64 + g*2;
        unsigned va = q[0], vb = q[1];
        a0 += bf2f((unsigned short)(va & 0xFFFFu));
        a1 += bf2f((unsigned short)(va >> 16));
        a2 += bf2f((unsigned short)(vb & 0xFFFFu));
        a3 += bf2f((unsigned short)(vb >> 16));
    }
    float di = Dinv[n];
    float b0, b1, b2, b3;
    if (c < 64){
        b0 = ldv(x, n*64 + c, bf);     b1 = ldv(x, n*64 + c + 1, bf);
        b2 = ldv(x, n*64 + c + 2, bf); b3 = ldv(x, n*64 + c + 3, bf);
    } else {
        int cc = c - 64;
        b0 = ldv(st, n*64 + cc, bf);     b1 = ldv(st, n*64 + cc + 1, bf);
        b2 = ldv(st, n*64 + cc + 2, bf); b3 = ldv(st, n*64 + cc + 3, bf);
    }
    float v0 = b0 + di*a0 + ldv(gb, c, bf);
    float v1 = b1 + di*a1 + ldv(gb, c + 1, bf);
    float v2 = b2 + di*a2 + ldv(gb, c + 2, bf);
    float v3 = b3 + di*a3 + ldv(gb, c + 3, bf);
    if (v0 < 0.f) v0 = 0.f;
    if (v1 < 0.f) v1 = 0.f;
    if (v2 < 0.f) v2 = 0.f;
    if (v3 < 0.f) v3 = 0.f;
    // row stats across the node's 32 lanes (128 values)
    float s  = v0 + v1 + v2 + v3;
    float sq = v0*v0 + v1*v1 + v2*v2 + v3*v3;
    for (int m = 1; m <= 16; m <<= 1){
        s  += __shfl_xor(s,  m);
        sq += __shfl_xor(sq, m);
    }
    float mu  = s * (1.f/128.f);
    float var = sq * (1.f/128.f) - mu*mu;
    if (var < 0.f) var = 0.f;
    float inv = 1.f / sqrtf(var + 1e-5f);
    float u0 = (v0 - mu)*inv*ldv(lng, c, bf)     + ldv(lnb, c, bf);
    float u1 = (v1 - mu)*inv*ldv(lng, c + 1, bf) + ldv(lnb, c + 1, bf);
    float u2 = (v2 - mu)*inv*ldv(lng, c + 2, bf) + ldv(lnb, c + 2, bf);
    float u3 = (v3 - mu)*inv*ldv(lng, c + 3, bf) + ldv(lnb, c + 3, bf);
    float z0 = 1.f/(1.f + expf(-u0));
    float z1 = 1.f/(1.f + expf(-u1));
    float z2 = 1.f/(1.f + expf(-u2));
    float z3 = 1.f/(1.f + expf(-u3));
    if (c < 64){
        float* o = zbuf + n*64 + c;
        o[0] = z0; o[1] = z1; o[2] = z2; o[3] = z3;
    } else {
        int cc = c - 64;
        float s0 = ldv(st, n*64 + cc, bf),     s1v = ldv(st, n*64 + cc + 1, bf),
              s2 = ldv(st, n*64 + cc + 2, bf), s3v = ldv(st, n*64 + cc + 3, bf);
        float* o = rs + n*64 + cc;
        o[0] = z0*s0; o[1] = z1*s1v; o[2] = z2*s2; o[3] = z3*s3v;
    }
}

// R29: fused node gather + cand prep + row-LN + tanh + GRU blend -> out.
// Thread per (node, 4-col group); node's 16 lanes wave-aligned; 4-step shfl.
__global__ void k_prep_fin_cand(const int* indptr_n, const int* Dc,
                                const unsigned short* nlist, const unsigned* mb,
                                const unsigned short* X1b, const float* Dinv,
                                const void* cbv, const void* crb,
                                const void* lng, const void* lnb,
                                const float* zbuf, const void* st,
                                void* out, const int* flag){
    int bf = *flag;
    int t = blockIdx.x*256 + threadIdx.x;
    if (t >= N_NODES*16) return;
    int n = t >> 4, g = t & 15;
    int c = g*4;
    int beg = indptr_n[n], cnt = Dc[n];
    float a0 = 0.f, a1 = 0.f, a2 = 0.f, a3 = 0.f;
    int j = 0;
    for (; j + 4 <= cnt; j += 4){
        int e0 = nlist[beg+j+0], e1 = nlist[beg+j+1],
            e2 = nlist[beg+j+2], e3 = nlist[beg+j+3];
        const unsigned* q0 = mb + e0*32 + g*2;
        const unsigned* q1 = mb + e1*32 + g*2;
        const unsigned* q2 = mb + e2*32 + g*2;
        const unsigned* q3 = mb + e3*32 + g*2;
        unsigned va0 = q0[0], vb0 = q0[1];
        unsigned va1 = q1[0], vb1 = q1[1];
        unsigned va2 = q2[0], vb2 = q2[1];
        unsigned va3 = q3[0], vb3 = q3[1];
        a0 += bf2f((unsigned short)(va0 & 0xFFFFu)); a1 += bf2f((unsigned short)(va0 >> 16));
        a2 += bf2f((unsigned short)(vb0 & 0xFFFFu)); a3 += bf2f((unsigned short)(vb0 >> 16));
        a0 += bf2f((unsigned short)(va1 & 0xFFFFu)); a1 += bf2f((unsigned short)(va1 >> 16));
        a2 += bf2f((unsigned short)(vb1 & 0xFFFFu)); a3 += bf2f((unsigned short)(vb1 >> 16));
        a0 += bf2f((unsigned short)(va2 & 0xFFFFu)); a1 += bf2f((unsigned short)(va2 >> 16));
        a2 += bf2f((unsigned short)(vb2 & 0xFFFFu)); a3 += bf2f((unsigned short)(vb2 >> 16));
        a0 += bf2f((unsigned short)(va3 & 0xFFFFu)); a1 += bf2f((unsigned short)(va3 >> 16));
        a2 += bf2f((unsigned short)(vb3 & 0xFFFFu)); a3 += bf2f((unsigned short)(vb3 >> 16));
    }
    for (; j < cnt; ++j){
        int e = nlist[beg + j];
        const unsigned* q = mb + e*32 + g*2;
        unsigned va = q[0], vb = q[1];
        a0 += bf2f((unsigned short)(va & 0xFFFFu));
        a1 += bf2f((unsigned short)(va >> 16));
        a2 += bf2f((unsigned short)(vb & 0xFFFFu));
        a3 += bf2f((unsigned short)(vb >> 16));
    }
    float di = Dinv[n];
    float v0 = bf2f(X1b[n*128 + 64 + c])     + ldv(crb, c, bf)     + di*a0 + ldv(cbv, c, bf);
    float v1 = bf2f(X1b[n*128 + 64 + c + 1]) + ldv(crb, c + 1, bf) + di*a1 + ldv(cbv, c + 1, bf);
    float v2 = bf2f(X1b[n*128 + 64 + c + 2]) + ldv(crb, c + 2, bf) + di*a2 + ldv(cbv, c + 2, bf);
    float v3 = bf2f(X1b[n*128 + 64 + c + 3]) + ldv(crb, c + 3, bf) + di*a3 + ldv(cbv, c + 3, bf);
    if (v0 < 0.f) v0 = 0.f;
    if (v1 < 0.f) v1 = 0.f;
    if (v2 < 0.f) v2 = 0.f;
    if (v3 < 0.f) v3 = 0.f;
    // row stats across the node's 16 lanes (64 values)
    float s  = v0 + v1 + v2 + v3;
    float sq = v0*v0 + v1*v1 + v2*v2 + v3*v3;
    for (int m = 1; m <= 8; m <<= 1){
        s  += __shfl_xor(s,  m);
        sq += __shfl_xor(sq, m);
    }
    float mu  = s * (1.f/64.f);
    float var = sq * (1.f/64.f) - mu*mu;
    if (var < 0.f) var = 0.f;
    float inv = 1.f / sqrtf(var + 1e-5f);
    float u0 = (v0 - mu)*inv*ldv(lng, c, bf)     + ldv(lnb, c, bf);
    float u1 = (v1 - mu)*inv*ldv(lng, c + 1, bf) + ldv(lnb, c + 1, bf);
    float u2 = (v2 - mu)*inv*ldv(lng, c + 2, bf) + ldv(lnb, c + 2, bf);
    float u3 = (v3 - mu)*inv*ldv(lng, c + 3, bf) + ldv(lnb, c + 3, bf);
    float h0 = tanhf(u0), h1 = tanhf(u1), h2 = tanhf(u2), h3 = tanhf(u3);
    int base = n*64 + c;
    float z0 = zbuf[base], z1 = zbuf[base+1], z2 = zbuf[base+2], z3 = zbuf[base+3];
    float s0 = ldv(st, base, bf),   s1v = ldv(st, base+1, bf),
          s2 = ldv(st, base+2, bf), s3v = ldv(st, base+3, bf);
    float r0 = (1.f - z0)*s0  + z0*h0;
    float r1 = (1.f - z1)*s1v + z1*h1;
    float r2 = (1.f - z2)*s2  + z2*h2;
    float r3 = (1.f - z3)*s3v + z3*h3;
    if (bf){
        unsigned short* o = (unsigned short*)out + base;
        o[0] = f2bf(r0); o[1] = f2bf(r1); o[2] = f2bf(r2); o[3] = f2bf(r3);
    } else {
        float* o = (float*)out + base;
        o[0] = r0; o[1] = r1; o[2] = r2; o[3] = r3;
    }
}

extern "C" void kernel_launch(void* const* d_in, const int* in_sizes, int n_in,
                              void* d_out, int out_size, void* d_ws, size_t ws_size,
                              hipStream_t stream){
    const void* x      = d_in[0];
    const void* state  = d_in[1];
    const int*  hidx   = (const int*)d_in[2];
    const void* hw     = d_in[3];
    const void* gate_W = d_in[4];
    const void* gate_b = d_in[5];
    const void* glng   = d_in[6];
    const void* glnb   = d_in[7];
    const void* cand_W = d_in[8];
    const void* cand_b = d_in[9];
    const void* clng   = d_in[10];
    const void* clnb   = d_in[11];
    const void* crW    = d_in[12];
    const void* crb    = d_in[13];
    (void)in_sizes; (void)n_in; (void)ws_size; (void)out_size;

    const int* nidx = hidx;
    const int* eidx = hidx + N_INC;

    const int NCH_N = (N_NODES + 127)/128;   // 391
    const int NCH_E = (N_EDGES + 127)/128;   // 79

    // ---- workspace (byte offsets, 256B-aligned, total ~73.5 MB) ----
    char* w = (char*)d_ws;
    int*   flag     = (int*)  (w);
    float* Dinv     = (float*)(w + 256);        // 50048 f (computed by k_dinv)
    int*   Bc       = (int*)  (w + 200448);     // 10048 i
    int*   Dc       = (int*)  (w + 240640);     // 50048 i
    float* Binv     = (float*)(w + 440832);     // 10048 f
    int*   indptr_n = (int*)  (w + 481024);     // 50048 i
    int*   gntail   = (int*)  (w + 681216);     // 98 i
    int*   getail   = (int*)  (w + 681216 + 4*NBK2); // 79 i (contiguous)
    int*   indptr_e = (int*)  (w + 881408);     // 10048 i
    int*   csum_n   = (int*)  (w + 961792);     // 512 i
    int*   cbase_n  = (int*)  (w + 963840);     // 512 i
    int*   csum_e   = (int*)  (w + 965888);     // 256 i
    int*   cbase_e  = (int*)  (w + 966912);     // 256 i
    unsigned short* nlist = (unsigned short*)(w + 967936);  // 800000 u16
    unsigned short* elist = (unsigned short*)(w + 2567936); // 800000 u16
    unsigned* mb    = (unsigned*)(w + 5767936); // 10000*64 u32 (=128 bf16 cols)
    unsigned short* X1b = (unsigned short*)(w + 8327936);   // 50000*128 u16
    // bin buffers live in the old P region (P no longer materialized):
    unsigned* nbuf  = (unsigned*)(w + 21127936);                      // 98*8960 u32 = 3.51MB
    unsigned* ebuf  = (unsigned*)(w + 21127936 + 4*NBK2*NGCAP);       // 79*11264 u32 = 3.56MB
    float* zbuf     = (float*)(w + 46727936);   // 50000*64 f
    float* rs       = (float*)(w + 59527936);   // 50000*64 f

    // dtype detect
    k_detect<<<1, 64, 0, stream>>>((const unsigned short*)hw, flag);

    // zero bucket tails (gntail+getail contiguous: 177 words)
    k_zero<<<1, 256, 0, stream>>>((float*)(w + 681216), NBK2 + EBK2);

    // ---- CSR build via owner-scan counting sort (512-entry tiles) ----
    k_bin3<<<(N_INC + 511)/512, 256, 0, stream>>>(nidx, eidx, gntail, nbuf,
                                                  getail, ebuf);
    k_hist2<<<NBK2 + EBK2, 256, 0, stream>>>(gntail, nbuf, Dc, getail, ebuf, Bc);
    k_binv<<<(N_EDGES + 255)/256, 256, 0, stream>>>(Bc, Binv);
    k_chunksum<<<(NCH_N + 255)/256, 256, 0, stream>>>(Dc, csum_n, N_NODES, NCH_N);
    k_chunkscan<<<1, 64, 0, stream>>>(csum_n, cbase_n, NCH_N);
    k_chunkfill<<<(NCH_N + 255)/256, 256, 0, stream>>>(Dc, cbase_n, indptr_n,
                                                       N_NODES, NCH_N);
    k_chunksum<<<(NCH_E + 255)/256, 256, 0, stream>>>(Bc, csum_e, N_EDGES, NCH_E);
    k_chunkscan<<<1, 64, 0, stream>>>(csum_e, cbase_e, NCH_E);
    k_chunkfill<<<(NCH_E + 255)/256, 256, 0, stream>>>(Bc, cbase_e, indptr_e,
                                                       N_EDGES, NCH_E);
    k_unbin2<<<NBK2 + EBK2, 256, 0, stream>>>(gntail, nbuf, indptr_n, nlist,
                                              getail, ebuf, indptr_e, elist);
    k_dinv<<<(N_NODES + 255)/256, 256, 0, stream>>>(indptr_n, Dc, nlist, hw, Dinv, flag);

    // ---- gate path (fused prep+LN+sigmoid) ----
    k_gemm_gate<<<(N_NODES + 63)/64, 256, 0, stream>>>(x, state, gate_W, X1b, flag);
    k_gather_e_gate<<<(N_EDGES*64 + 255)/256, 256, 0, stream>>>(indptr_e, Bc, elist,
                                                                X1b, hw, Binv, mb, flag);
    k_prep_fin_gate<<<(N_NODES*32 + 255)/256, 256, 0, stream>>>(indptr_n, Dc, nlist,
                                                                mb, x, state, Dinv,
                                                                gate_b, glng, glnb,
                                                                zbuf, rs, flag);

    // ---- candidate path (fused prep+LN+tanh+blend) ----
    k_gemm_cand<<<(N_NODES + 63)/64, 256, 0, stream>>>(x, rs, cand_W, crW, X1b, flag);
    k_gather_e2<<<(N_EDGES*32 + 255)/256, 256, 0, stream>>>(indptr_e, Bc, elist, X1b,
                                                            hw, Binv, mb, 0, 32, flag);
    k_prep_fin_cand<<<(N_NODES*16 + 255)/256, 256, 0, stream>>>(indptr_n, Dc, nlist,
                                                                mb, X1b, Dinv, cand_b,
                                                                crb, clng, clnb,
                                                                zbuf, state,
                                                                d_out, flag);
}